// Round 4
// baseline (1995.011 us; speedup 1.0000x reference)
//
#include <hip/hip_runtime.h>

#define NSV 20
#define SS  1000

typedef __bf16 bf16_t;
typedef __bf16 bf16x8 __attribute__((ext_vector_type(8)));
typedef float  f32x4  __attribute__((ext_vector_type(4)));

__device__ __forceinline__ float selu_f(float v) {
    const float scale = 1.0507009873554805f;
    const float alpha = 1.6732632423543772f;
    return v > 0.f ? scale * v : scale * alpha * expm1f(v);
}

// ---------------------------------------------------------------------------
// RNN kernel: one block per batch row, 512 threads (8 waves, pinned 2/EU).
// Thread (rowg, colg) = (tid>>3, tid&7) computes rows {2*rowg, 2*rowg+1} over
// cols [colg*16, colg*16+16): register blocking R=2 halves LDS traffic vs R=1.
// Weights register-resident (waves_per_eu(2,2) -> 256-VGPR budget).
// Rotation (i+colg)&3 baked into weight LOAD order: literal register indices,
// rotated LDS addresses -> <=2-way bank aliasing (free).
// Reduction: shfl_xor 1,2,4 across the 8 col-groups.
// ---------------------------------------------------------------------------
__global__ __launch_bounds__(512, 2) __attribute__((amdgpu_waves_per_eu(2, 2)))
void rnn_kernel(
    const float* __restrict__ x,
    const float* __restrict__ gw0, const float* __restrict__ gb0,
    const float* __restrict__ gw1, const float* __restrict__ gb1,
    const float* __restrict__ gw2, const float* __restrict__ gb2,
    const float* __restrict__ gw3, const float* __restrict__ gb3,
    float* __restrict__ statevar)
{
    const int b    = blockIdx.x;
    const int tid  = threadIdx.x;
    const int rowg = tid >> 3;   // 0..63
    const int colg = tid & 7;    // 0..7
    const int r0   = rowg * 2;   // rows r0, r0+1

    __shared__ __align__(16) float h0buf[32];   // [eps(6), sv(20), pad0(6)]
    __shared__ __align__(16) float hA[128];
    __shared__ __align__(16) float hB[128];
    __shared__ __align__(16) float hC[128];
    __shared__ float sdt[2];

    // ---- weights into registers (rotation baked into load order) ----
    float4 w0v[2];
#pragma unroll
    for (int r = 0; r < 2; ++r) {
        float4 w;
        float* wp = (float*)&w;
#pragma unroll
        for (int k = 0; k < 4; ++k) {
            int c = colg * 4 + k;
            wp[k] = (c < 26) ? gw0[(r0 + r) * 26 + c] : 0.f;
        }
        w0v[r] = w;
    }
    float4 w1v[2][4], w2v[2][4], w3v[2][4];
#pragma unroll
    for (int r = 0; r < 2; ++r)
#pragma unroll
        for (int i = 0; i < 4; ++i) {
            const int cg = (i + colg) & 3;
            w1v[r][i] = *(const float4*)&gw1[(r0 + r) * 128 + colg * 16 + cg * 4];
            w2v[r][i] = *(const float4*)&gw2[(r0 + r) * 128 + colg * 16 + cg * 4];
        }
    if (rowg < NSV / 2) {
#pragma unroll
        for (int r = 0; r < 2; ++r)
#pragma unroll
            for (int i = 0; i < 4; ++i) {
                const int cg = (i + colg) & 3;
                w3v[r][i] = *(const float4*)&gw3[(r0 + r) * 128 + colg * 16 + cg * 4];
            }
    }
    const float2 b0p = *(const float2*)&gb0[r0];
    const float2 b1p = *(const float2*)&gb1[r0];
    const float2 b2p = *(const float2*)&gb2[r0];
    const float2 b3p = (rowg < NSV / 2) ? *(const float2*)&gb3[r0]
                                        : make_float2(0.f, 0.f);

    const float* xb = x + b * (SS * 13);

    // ---- init: h0 = [eps(0), 0...], dt(0), statevar[:,0,:] = 0 ----
    if (tid < 6)                 h0buf[tid] = xb[1 + tid];
    else if (tid < 32)           h0buf[tid] = 0.f;
    if (tid == 32)               sdt[0] = xb[13] - xb[0];
    if (tid < NSV)               statevar[b * (SS * NSV) + tid] = 0.f;
    __syncthreads();

#define RED8(S) do {                     \
        S += __shfl_xor(S, 1, 64);       \
        S += __shfl_xor(S, 2, 64);       \
        S += __shfl_xor(S, 4, 64);       \
    } while (0)

    // 16-wide x 2-row dot; rotated LDS float4 reads, literal register indices.
#define DOT16(WV, H4, OUT0, OUT1) do {                                \
        float4 a0 = {0.f,0.f,0.f,0.f}, a1 = {0.f,0.f,0.f,0.f};        \
        _Pragma("unroll")                                             \
        for (int i_ = 0; i_ < 4; ++i_) {                              \
            float4 hv_ = (H4)[(i_ + colg) & 3];                       \
            a0.x = fmaf(WV[0][i_].x, hv_.x, a0.x);                    \
            a0.y = fmaf(WV[0][i_].y, hv_.y, a0.y);                    \
            a0.z = fmaf(WV[0][i_].z, hv_.z, a0.z);                    \
            a0.w = fmaf(WV[0][i_].w, hv_.w, a0.w);                    \
            a1.x = fmaf(WV[1][i_].x, hv_.x, a1.x);                    \
            a1.y = fmaf(WV[1][i_].y, hv_.y, a1.y);                    \
            a1.z = fmaf(WV[1][i_].z, hv_.z, a1.z);                    \
            a1.w = fmaf(WV[1][i_].w, hv_.w, a1.w);                    \
        }                                                             \
        OUT0 = (a0.x + a0.y) + (a0.z + a0.w);                         \
        OUT1 = (a1.x + a1.y) + (a1.z + a1.w);                         \
    } while (0)

    for (int t = 0; t < SS - 1; ++t) {
        // L0: 32(padded) -> 128
        {
            float4 hv = ((const float4*)h0buf)[colg];
            float s0 = fmaf(w0v[0].x, hv.x, fmaf(w0v[0].y, hv.y,
                       fmaf(w0v[0].z, hv.z, w0v[0].w * hv.w)));
            float s1 = fmaf(w0v[1].x, hv.x, fmaf(w0v[1].y, hv.y,
                       fmaf(w0v[1].z, hv.z, w0v[1].w * hv.w)));
            RED8(s0); RED8(s1);
            if (colg == 0)
                *(float2*)&hA[r0] = make_float2(selu_f(s0 + b0p.x),
                                                selu_f(s1 + b0p.y));
        }
        __syncthreads();

        // L1: 128 -> 128  (hA -> hB)
        {
            float s0, s1;
            DOT16(w1v, ((const float4*)hA) + colg * 4, s0, s1);
            RED8(s0); RED8(s1);
            if (colg == 0)
                *(float2*)&hB[r0] = make_float2(selu_f(s0 + b1p.x),
                                                selu_f(s1 + b1p.y));
        }
        __syncthreads();

        // L2: 128 -> 128  (hB -> hC)
        {
            float s0, s1;
            DOT16(w2v, ((const float4*)hB) + colg * 4, s0, s1);
            RED8(s0); RED8(s1);
            if (colg == 0)
                *(float2*)&hC[r0] = make_float2(selu_f(s0 + b2p.x),
                                                selu_f(s1 + b2p.y));
        }
        __syncthreads();

        // L3: 128 -> 20, integrate sv; prefetch eps/dt for t+1
        if (rowg < NSV / 2) {
            float s0, s1;
            DOT16(w3v, ((const float4*)hC) + colg * 4, s0, s1);
            RED8(s0); RED8(s1);
            if (colg == 0) {
                const float dtv = sdt[t & 1];
                float ns0 = h0buf[6 + r0] + dtv * (s0 + b3p.x);
                float ns1 = h0buf[7 + r0] + dtv * (s1 + b3p.y);
                *(float2*)&h0buf[6 + r0] = make_float2(ns0, ns1);
                *(float2*)&statevar[b * (SS * NSV) + (t + 1) * NSV + r0] =
                    make_float2(ns0, ns1);
            }
        }
        if (tid >= 128 && tid < 134)
            h0buf[tid - 128] = xb[(t + 1) * 13 + 1 + (tid - 128)];
        if (tid == 140 && t + 2 < SS)
            sdt[(t + 1) & 1] = xb[(t + 2) * 13] - xb[(t + 1) * 13];
        __syncthreads();
    }
#undef DOT16
#undef RED8
}

// ---------------------------------------------------------------------------
// Weight prep: fp32 -> bf16, pad fw3 from [6][256] to [16][256] with zeros.
// ---------------------------------------------------------------------------
__global__ void prep_weights(
    const float* __restrict__ fw0, const float* __restrict__ fw1,
    const float* __restrict__ fw2, const float* __restrict__ fw3,
    bf16_t* __restrict__ w0b, bf16_t* __restrict__ w1b,
    bf16_t* __restrict__ w2b, bf16_t* __restrict__ w3b)
{
    const int i      = blockIdx.x * blockDim.x + threadIdx.x;
    const int stride = gridDim.x * blockDim.x;
    for (int k = i; k < 256 * 32;  k += stride) w0b[k] = (bf16_t)fw0[k];
    for (int k = i; k < 256 * 256; k += stride) w1b[k] = (bf16_t)fw1[k];
    for (int k = i; k < 256 * 256; k += stride) w2b[k] = (bf16_t)fw2[k];
    for (int k = i; k < 16 * 256;  k += stride) {
        int row = k >> 8, col = k & 255;
        w3b[k] = (row < 6) ? (bf16_t)fw3[row * 256 + col] : (bf16_t)0.f;
    }
}

// ---------------------------------------------------------------------------
// Fused F-MLP: 64-row tiles, bf16 MFMA 16x16x32, fp32 accumulate.
// ---------------------------------------------------------------------------
#define LDA 264   // 256 + 8 pad

template <int K>
__device__ __forceinline__ void mlp_layer(
    bf16_t* __restrict__ A, const bf16_t* __restrict__ Wb,
    const float* __restrict__ bias, int wave, int lane, bool do_selu)
{
    f32x4 acc[4][4];
#pragma unroll
    for (int mt = 0; mt < 4; ++mt)
#pragma unroll
        for (int nt = 0; nt < 4; ++nt) acc[mt][nt] = (f32x4){0.f, 0.f, 0.f, 0.f};

    const int colbase = wave * 64;
    const int mrow = lane & 15;
    const int quad = lane >> 4;

#pragma unroll
    for (int ks = 0; ks < K / 32; ++ks) {
        bf16x8 af[4], bfr[4];
#pragma unroll
        for (int mt = 0; mt < 4; ++mt)
            af[mt] = *(const bf16x8*)&A[(mt * 16 + mrow) * LDA + ks * 32 + quad * 8];
#pragma unroll
        for (int nt = 0; nt < 4; ++nt)
            bfr[nt] = *(const bf16x8*)&Wb[(colbase + nt * 16 + mrow) * K + ks * 32 + quad * 8];
#pragma unroll
        for (int mt = 0; mt < 4; ++mt)
#pragma unroll
            for (int nt = 0; nt < 4; ++nt)
                acc[mt][nt] = __builtin_amdgcn_mfma_f32_16x16x32_bf16(
                    af[mt], bfr[nt], acc[mt][nt], 0, 0, 0);
    }
    __syncthreads();   // all waves done reading A before overwrite

#pragma unroll
    for (int nt = 0; nt < 4; ++nt) {
        const int col = colbase + nt * 16 + mrow;
        const float bv = bias[col];
#pragma unroll
        for (int mt = 0; mt < 4; ++mt) {
#pragma unroll
            for (int rI = 0; rI < 4; ++rI) {
                int row = mt * 16 + quad * 4 + rI;
                float v = acc[mt][nt][rI] + bv;
                if (do_selu) v = selu_f(v);
                A[row * LDA + col] = (bf16_t)v;
            }
        }
    }
    __syncthreads();
}

__global__ __launch_bounds__(256) void fmlp_kernel(
    const float* __restrict__ x, const float* __restrict__ statevar,
    const bf16_t* __restrict__ w0b, const bf16_t* __restrict__ w1b,
    const bf16_t* __restrict__ w2b, const bf16_t* __restrict__ w3b,
    const float* __restrict__ fb0, const float* __restrict__ fb1,
    const float* __restrict__ fb2, const float* __restrict__ fb3,
    float* __restrict__ out)
{
    __shared__ bf16_t A[64 * LDA];

    const int tid  = threadIdx.x;
    const int wave = tid >> 6;
    const int lane = tid & 63;
    const int r0   = blockIdx.x * 64;

    // ---- build input tile: [strain(6), strain_dot(6), statevar(20)] ----
    {
        const int r = tid >> 2;       // 0..63
        const int q = tid & 3;        // 8-col group
        const int g = r0 + r;         // global row = b*1000 + s
        const float* xr  = x + g * 13;
        const float* svr = statevar + g * NSV;
#pragma unroll
        for (int i = 0; i < 8; ++i) {
            int c = q * 8 + i;
            float v = (c < 12) ? xr[c + 1] : svr[c - 12];
            A[r * LDA + c] = (bf16_t)v;
        }
    }
    __syncthreads();

    mlp_layer<32>(A, w0b, fb0, wave, lane, true);
    mlp_layer<256>(A, w1b, fb1, wave, lane, true);
    mlp_layer<256>(A, w2b, fb2, wave, lane, true);

    // ---- L3: 256 -> 6 (padded to N=16), waves split rows ----
    {
        const int mrow = lane & 15;
        const int quad = lane >> 4;
        f32x4 acc = (f32x4){0.f, 0.f, 0.f, 0.f};
#pragma unroll
        for (int ks = 0; ks < 8; ++ks) {
            bf16x8 af  = *(const bf16x8*)&A[(wave * 16 + mrow) * LDA + ks * 32 + quad * 8];
            bf16x8 bfr = *(const bf16x8*)&w3b[mrow * 256 + ks * 32 + quad * 8];
            acc = __builtin_amdgcn_mfma_f32_16x16x32_bf16(af, bfr, acc, 0, 0, 0);
        }
        const int col = mrow;
        if (col < 6) {
            const float bv = fb3[col];
#pragma unroll
            for (int rI = 0; rI < 4; ++rI) {
                int row = wave * 16 + quad * 4 + rI;
                int g = r0 + row;
                out[g * 6 + col] = acc[rI] + bv;
            }
        }
    }
}

// ---------------------------------------------------------------------------
extern "C" void kernel_launch(void* const* d_in, const int* in_sizes, int n_in,
                              void* d_out, int out_size, void* d_ws, size_t ws_size,
                              hipStream_t stream)
{
    const float* x   = (const float*)d_in[0];
    const float* gw0 = (const float*)d_in[1];
    const float* gb0 = (const float*)d_in[2];
    const float* gw1 = (const float*)d_in[3];
    const float* gb1 = (const float*)d_in[4];
    const float* gw2 = (const float*)d_in[5];
    const float* gb2 = (const float*)d_in[6];
    const float* gw3 = (const float*)d_in[7];
    const float* gb3 = (const float*)d_in[8];
    const float* fw0 = (const float*)d_in[9];
    const float* fb0 = (const float*)d_in[10];
    const float* fw1 = (const float*)d_in[11];
    const float* fb1 = (const float*)d_in[12];
    const float* fw2 = (const float*)d_in[13];
    const float* fb2 = (const float*)d_in[14];
    const float* fw3 = (const float*)d_in[15];
    const float* fb3 = (const float*)d_in[16];

    // workspace layout
    float* statevar = (float*)d_ws;                              // 256*1000*20 fp32
    bf16_t* w0b = (bf16_t*)((char*)d_ws + 20480000);
    bf16_t* w1b = w0b + 256 * 32;
    bf16_t* w2b = w1b + 256 * 256;
    bf16_t* w3b = w2b + 256 * 256;

    prep_weights<<<64, 256, 0, stream>>>(fw0, fw1, fw2, fw3, w0b, w1b, w2b, w3b);
    rnn_kernel<<<256, 512, 0, stream>>>(x, gw0, gb0, gw1, gb1, gw2, gb2, gw3, gb3, statevar);
    fmlp_kernel<<<4000, 256, 0, stream>>>(x, statevar, w0b, w1b, w2b, w3b,
                                          fb0, fb1, fb2, fb3, (float*)d_out);
}

// Round 5
// 1673.527 us; speedup vs baseline: 1.1921x; 1.1921x over previous
//
#include <hip/hip_runtime.h>

#define NSV 20
#define SS  1000

typedef __bf16 bf16_t;
typedef __bf16 bf16x8 __attribute__((ext_vector_type(8)));
typedef float  f32x4  __attribute__((ext_vector_type(4)));

__device__ __forceinline__ float selu_f(float v) {
    const float scale = 1.0507009873554805f;
    const float alpha = 1.6732632423543772f;
    return v > 0.f ? scale * v : scale * alpha * expm1f(v);
}

// Pin a value into a VGPR: empty asm that "modifies" it, so the compiler
// cannot re-materialize it by re-loading from global inside the t-loop.
#define PIN(v) asm volatile("" : "+v"(v))

// ---------------------------------------------------------------------------
// RNN kernel: one block per batch row, 512 threads (8 waves).
// Threads (4j..4j+3) compute hidden unit j; each holds a 32-wide slice of the
// weight row in registers (pinned — see PIN). Bank-conflict-free via
// quarter-rotated LDS reads; rotation baked into weight LOAD order so every
// register index in the inner loop is a compile-time literal.
// ---------------------------------------------------------------------------
__global__ __launch_bounds__(512, 2) void rnn_kernel(
    const float* __restrict__ x,
    const float* __restrict__ gw0, const float* __restrict__ gb0,
    const float* __restrict__ gw1, const float* __restrict__ gb1,
    const float* __restrict__ gw2, const float* __restrict__ gb2,
    const float* __restrict__ gw3, const float* __restrict__ gb3,
    float* __restrict__ statevar)
{
    const int b   = blockIdx.x;
    const int tid = threadIdx.x;
    const int j   = tid >> 2;   // hidden unit 0..127
    const int q   = tid & 3;    // quarter 0..3

    __shared__ __align__(16) float h0buf[28];   // [eps(6), sv(20), pad0(2)]
    __shared__ __align__(16) float hA[128];
    __shared__ __align__(16) float hB[128];
    __shared__ __align__(16) float hC[128];
    __shared__ float sdt[2];

    // ---- weights into registers, rotated column order (static reg indices) --
    float w0[7];
#pragma unroll
    for (int i = 0; i < 7; ++i) {
        int c = q * 7 + i;                      // 0..27
        w0[i] = (c < 26) ? gw0[j * 26 + c] : 0.f;
    }
    float w1[32], w2[32], w3[32];
#pragma unroll
    for (int i = 0; i < 8; ++i) {
        const int cg = ((i + 2 * q) & 7) * 4;   // rotated column group
#pragma unroll
        for (int k = 0; k < 4; ++k)
            w1[i * 4 + k] = gw1[j * 128 + q * 32 + cg + k];
    }
#pragma unroll
    for (int i = 0; i < 8; ++i) {
        const int cg = ((i + 2 * q) & 7) * 4;
#pragma unroll
        for (int k = 0; k < 4; ++k)
            w2[i * 4 + k] = gw2[j * 128 + q * 32 + cg + k];
    }
    if (j < NSV) {
#pragma unroll
        for (int i = 0; i < 8; ++i) {
            const int cg = ((i + 2 * q) & 7) * 4;
#pragma unroll
            for (int k = 0; k < 4; ++k)
                w3[i * 4 + k] = gw3[j * 128 + q * 32 + cg + k];
        }
    } else {
#pragma unroll
        for (int i = 0; i < 32; ++i) w3[i] = 0.f;
    }
    float b0 = gb0[j];
    float b1 = gb1[j];
    float b2 = gb2[j];
    float b3 = (j < NSV) ? gb3[j] : 0.f;

    // ---- pin everything loop-invariant into VGPRs ----
#pragma unroll
    for (int i = 0; i < 7; ++i)  PIN(w0[i]);
#pragma unroll
    for (int i = 0; i < 32; ++i) PIN(w1[i]);
#pragma unroll
    for (int i = 0; i < 32; ++i) PIN(w2[i]);
#pragma unroll
    for (int i = 0; i < 32; ++i) PIN(w3[i]);
    PIN(b0); PIN(b1); PIN(b2); PIN(b3);

    const float* xb = x + b * (SS * 13);

    // ---- init: h0 = [eps(0), sv0=0, pad=0], dt(0), statevar[:,0,:]=0 ----
    if (tid < 6)                 h0buf[tid] = xb[1 + tid];
    else if (tid < 28)           h0buf[tid] = 0.f;
    if (tid == 28)               sdt[0] = xb[13] - xb[0];
    if (tid < NSV)               statevar[b * (SS * NSV) + tid] = 0.f;
    __syncthreads();

    // 32-wide dot: LDS address rotated per quarter (conflict-free broadcast),
    // register indices all literal.
#define DOT32(W, BASE, OUT) do {                                    \
        const float4* h4_ = (const float4*)(BASE);                  \
        float s0_ = 0.f, s1_ = 0.f, s2_ = 0.f, s3_ = 0.f;           \
        _Pragma("unroll")                                           \
        for (int i_ = 0; i_ < 8; ++i_) {                            \
            float4 hv_ = h4_[(i_ + 2 * q) & 7];                     \
            s0_ = fmaf(W[4*i_+0], hv_.x, s0_);                      \
            s1_ = fmaf(W[4*i_+1], hv_.y, s1_);                      \
            s2_ = fmaf(W[4*i_+2], hv_.z, s2_);                      \
            s3_ = fmaf(W[4*i_+3], hv_.w, s3_);                      \
        }                                                           \
        OUT = (s0_ + s1_) + (s2_ + s3_);                            \
    } while (0)

    for (int t = 0; t < SS - 1; ++t) {
        // L0: 28 -> 128 (h0buf[26..27] are permanent zeros)
        {
            float s0 = 0.f, s1 = 0.f;
            const float* hh = &h0buf[q * 7];
#pragma unroll
            for (int i = 0; i < 6; i += 2) {
                s0 = fmaf(w0[i + 0], hh[i + 0], s0);
                s1 = fmaf(w0[i + 1], hh[i + 1], s1);
            }
            s0 = fmaf(w0[6], hh[6], s0);
            float s = s0 + s1;
            s += __shfl_xor(s, 1, 64);
            s += __shfl_xor(s, 2, 64);
            if (q == 0) hA[j] = selu_f(s + b0);
        }
        __syncthreads();

        // L1: 128 -> 128  (hA -> hB)
        {
            float s;
            DOT32(w1, &hA[q * 32], s);
            s += __shfl_xor(s, 1, 64);
            s += __shfl_xor(s, 2, 64);
            if (q == 0) hB[j] = selu_f(s + b1);
        }
        __syncthreads();

        // L2: 128 -> 128  (hB -> hC)
        {
            float s;
            DOT32(w2, &hB[q * 32], s);
            s += __shfl_xor(s, 1, 64);
            s += __shfl_xor(s, 2, 64);
            if (q == 0) hC[j] = selu_f(s + b2);
        }
        __syncthreads();

        // L3: 128 -> 20, integrate sv into h0buf; prefetch eps/dt for t+1
        if (j < NSV) {
            float s;
            DOT32(w3, &hC[q * 32], s);
            s += __shfl_xor(s, 1, 64);
            s += __shfl_xor(s, 2, 64);
            if (q == 0) {
                float svd = s + b3;
                float ns  = h0buf[6 + j] + sdt[t & 1] * svd;
                h0buf[6 + j] = ns;
                statevar[b * (SS * NSV) + (t + 1) * NSV + j] = ns;
            }
        }
        if (tid >= 128 && tid < 134)
            h0buf[tid - 128] = xb[(t + 1) * 13 + 1 + (tid - 128)];
        if (tid == 140 && t + 2 < SS)
            sdt[(t + 1) & 1] = xb[(t + 2) * 13] - xb[(t + 1) * 13];
        __syncthreads();
    }
#undef DOT32
}

// ---------------------------------------------------------------------------
// Weight prep: fp32 -> bf16, pad fw3 from [6][256] to [16][256] with zeros.
// ---------------------------------------------------------------------------
__global__ void prep_weights(
    const float* __restrict__ fw0, const float* __restrict__ fw1,
    const float* __restrict__ fw2, const float* __restrict__ fw3,
    bf16_t* __restrict__ w0b, bf16_t* __restrict__ w1b,
    bf16_t* __restrict__ w2b, bf16_t* __restrict__ w3b)
{
    const int i      = blockIdx.x * blockDim.x + threadIdx.x;
    const int stride = gridDim.x * blockDim.x;
    for (int k = i; k < 256 * 32;  k += stride) w0b[k] = (bf16_t)fw0[k];
    for (int k = i; k < 256 * 256; k += stride) w1b[k] = (bf16_t)fw1[k];
    for (int k = i; k < 256 * 256; k += stride) w2b[k] = (bf16_t)fw2[k];
    for (int k = i; k < 16 * 256;  k += stride) {
        int row = k >> 8, col = k & 255;
        w3b[k] = (row < 6) ? (bf16_t)fw3[row * 256 + col] : (bf16_t)0.f;
    }
}

// ---------------------------------------------------------------------------
// Fused F-MLP: 64-row tiles, bf16 MFMA 16x16x32, fp32 accumulate.
// ---------------------------------------------------------------------------
#define LDA 264   // 256 + 8 pad

template <int K>
__device__ __forceinline__ void mlp_layer(
    bf16_t* __restrict__ A, const bf16_t* __restrict__ Wb,
    const float* __restrict__ bias, int wave, int lane, bool do_selu)
{
    f32x4 acc[4][4];
#pragma unroll
    for (int mt = 0; mt < 4; ++mt)
#pragma unroll
        for (int nt = 0; nt < 4; ++nt) acc[mt][nt] = (f32x4){0.f, 0.f, 0.f, 0.f};

    const int colbase = wave * 64;
    const int mrow = lane & 15;
    const int quad = lane >> 4;

#pragma unroll
    for (int ks = 0; ks < K / 32; ++ks) {
        bf16x8 af[4], bfr[4];
#pragma unroll
        for (int mt = 0; mt < 4; ++mt)
            af[mt] = *(const bf16x8*)&A[(mt * 16 + mrow) * LDA + ks * 32 + quad * 8];
#pragma unroll
        for (int nt = 0; nt < 4; ++nt)
            bfr[nt] = *(const bf16x8*)&Wb[(colbase + nt * 16 + mrow) * K + ks * 32 + quad * 8];
#pragma unroll
        for (int mt = 0; mt < 4; ++mt)
#pragma unroll
            for (int nt = 0; nt < 4; ++nt)
                acc[mt][nt] = __builtin_amdgcn_mfma_f32_16x16x32_bf16(
                    af[mt], bfr[nt], acc[mt][nt], 0, 0, 0);
    }
    __syncthreads();   // all waves done reading A before overwrite

#pragma unroll
    for (int nt = 0; nt < 4; ++nt) {
        const int col = colbase + nt * 16 + mrow;
        const float bv = bias[col];
#pragma unroll
        for (int mt = 0; mt < 4; ++mt) {
#pragma unroll
            for (int rI = 0; rI < 4; ++rI) {
                int row = mt * 16 + quad * 4 + rI;
                float v = acc[mt][nt][rI] + bv;
                if (do_selu) v = selu_f(v);
                A[row * LDA + col] = (bf16_t)v;
            }
        }
    }
    __syncthreads();
}

__global__ __launch_bounds__(256) void fmlp_kernel(
    const float* __restrict__ x, const float* __restrict__ statevar,
    const bf16_t* __restrict__ w0b, const bf16_t* __restrict__ w1b,
    const bf16_t* __restrict__ w2b, const bf16_t* __restrict__ w3b,
    const float* __restrict__ fb0, const float* __restrict__ fb1,
    const float* __restrict__ fb2, const float* __restrict__ fb3,
    float* __restrict__ out)
{
    __shared__ bf16_t A[64 * LDA];

    const int tid  = threadIdx.x;
    const int wave = tid >> 6;
    const int lane = tid & 63;
    const int r0   = blockIdx.x * 64;

    // ---- build input tile: [strain(6), strain_dot(6), statevar(20)] ----
    {
        const int r = tid >> 2;       // 0..63
        const int q = tid & 3;        // 8-col group
        const int g = r0 + r;         // global row = b*1000 + s
        const float* xr  = x + g * 13;
        const float* svr = statevar + g * NSV;
#pragma unroll
        for (int i = 0; i < 8; ++i) {
            int c = q * 8 + i;
            float v = (c < 12) ? xr[c + 1] : svr[c - 12];
            A[r * LDA + c] = (bf16_t)v;
        }
    }
    __syncthreads();

    mlp_layer<32>(A, w0b, fb0, wave, lane, true);
    mlp_layer<256>(A, w1b, fb1, wave, lane, true);
    mlp_layer<256>(A, w2b, fb2, wave, lane, true);

    // ---- L3: 256 -> 6 (padded to N=16), waves split rows ----
    {
        const int mrow = lane & 15;
        const int quad = lane >> 4;
        f32x4 acc = (f32x4){0.f, 0.f, 0.f, 0.f};
#pragma unroll
        for (int ks = 0; ks < 8; ++ks) {
            bf16x8 af  = *(const bf16x8*)&A[(wave * 16 + mrow) * LDA + ks * 32 + quad * 8];
            bf16x8 bfr = *(const bf16x8*)&w3b[mrow * 256 + ks * 32 + quad * 8];
            acc = __builtin_amdgcn_mfma_f32_16x16x32_bf16(af, bfr, acc, 0, 0, 0);
        }
        const int col = mrow;
        if (col < 6) {
            const float bv = fb3[col];
#pragma unroll
            for (int rI = 0; rI < 4; ++rI) {
                int row = wave * 16 + quad * 4 + rI;
                int g = r0 + row;
                out[g * 6 + col] = acc[rI] + bv;
            }
        }
    }
}

// ---------------------------------------------------------------------------
extern "C" void kernel_launch(void* const* d_in, const int* in_sizes, int n_in,
                              void* d_out, int out_size, void* d_ws, size_t ws_size,
                              hipStream_t stream)
{
    const float* x   = (const float*)d_in[0];
    const float* gw0 = (const float*)d_in[1];
    const float* gb0 = (const float*)d_in[2];
    const float* gw1 = (const float*)d_in[3];
    const float* gb1 = (const float*)d_in[4];
    const float* gw2 = (const float*)d_in[5];
    const float* gb2 = (const float*)d_in[6];
    const float* gw3 = (const float*)d_in[7];
    const float* gb3 = (const float*)d_in[8];
    const float* fw0 = (const float*)d_in[9];
    const float* fb0 = (const float*)d_in[10];
    const float* fw1 = (const float*)d_in[11];
    const float* fb1 = (const float*)d_in[12];
    const float* fw2 = (const float*)d_in[13];
    const float* fb2 = (const float*)d_in[14];
    const float* fw3 = (const float*)d_in[15];
    const float* fb3 = (const float*)d_in[16];

    // workspace layout
    float* statevar = (float*)d_ws;                              // 256*1000*20 fp32
    bf16_t* w0b = (bf16_t*)((char*)d_ws + 20480000);
    bf16_t* w1b = w0b + 256 * 32;
    bf16_t* w2b = w1b + 256 * 256;
    bf16_t* w3b = w2b + 256 * 256;

    prep_weights<<<64, 256, 0, stream>>>(fw0, fw1, fw2, fw3, w0b, w1b, w2b, w3b);
    rnn_kernel<<<256, 512, 0, stream>>>(x, gw0, gb0, gw1, gb1, gw2, gb2, gw3, gb3, statevar);
    fmlp_kernel<<<4000, 256, 0, stream>>>(x, statevar, w0b, w1b, w2b, w3b,
                                          fb0, fb1, fb2, fb3, (float*)d_out);
}